// Round 13
// baseline (4209.995 us; speedup 1.0000x reference)
//
#include <hip/hip_runtime.h>
#include <hip/hip_bf16.h>
#include <hip/hip_fp16.h>

// LSTM_RNN: B=128, T=512, E=256, U=512. R13 = R11 skeleton with the
// producer-side drain deleted: tag-in-data H + per-wave hint flags.
//   - Layout (R10/R11-proven): 128 wgs = 8 domains (d = bid&7, 16 rows,
//     XCD-local under round-robin) x 16 slices (32 units / 128 gate cols).
//     Weights in VGPRs; LDS padded to 96 KB -> 1 wg/CU.
//   - Publish: kh0 epilogue waves store TAGGED h (u32 = (t+1)<<16 | fp16,
//     agent relaxed, fire-and-forget -- no vmcnt drain), then EACH wave's
//     lane0 stores a volatile per-wave flag (hint; lands in XCD L2). No B4:
//     the R11 __syncthreads-before-flag cost vmcnt(0) = LLC store acks
//     (~0.3-0.4us) on the critical path every step.
//   - Consume: budgeted volatile poll of the domain's 64 wave-flags (one
//     load/lane/round, L2-cheap), then R4-proven PARALLEL agent tagged
//     masked retry (8 u64 chunks/wave). Tags are the real gate: correct and
//     live for ANY wg->XCD mapping, any store ordering, flag losses, etc.
//   - 2 barriers/step (B2 slab, B3 partials). WAR: R4 parity induction
//     (per-word tag gating; a wg writes h_{t+2} only after all wgs consumed
//     h_t -- induction through the tag gate, no end barrier needed).
//   - No init kernels: t=0 skips consumption (h0=0); 0xAAAA poison tags /
//     0xAAAAAAAA flags never match t in [1,512].
// ws layout (~34.1 MiB):
//   X     fp16 [T][B][E]       @ 0          (33,554,432 B)
//   Ht    u32  [2][8][16][512] @ 33,554,432 (524,288 B)   tagged h
//   FlagA u32  [2][8][64]      @ 34,078,720 (4,096 B)     volatile hint flags

#define B_ 128
#define T_ 512
#define E_ 256
#define U_ 512
#define NWG_ 128
#define HROW_ 516   // Hs row stride (halves)

typedef __attribute__((ext_vector_type(4))) _Float16 half4;
typedef __attribute__((ext_vector_type(4))) float floatx4;
typedef unsigned long long u64t;
typedef unsigned int u32t;

#define MFMA16 __builtin_amdgcn_mfma_f32_16x16x16f16

__device__ __forceinline__ float sigmf(float x) { return 1.0f / (1.0f + __expf(-x)); }
__device__ __forceinline__ float tanh_f(float x) { return 2.0f / (1.0f + __expf(-2.0f * x)) - 1.0f; }

// X[t][b][e] = (fp16) emb[sentence[b][t]][e]; one thread = 8 elements.
__global__ void prep_x_kernel(const int* __restrict__ sent,
                              const float* __restrict__ emb,
                              _Float16* __restrict__ X) {
  int gid = blockIdx.x * blockDim.x + threadIdx.x;  // 2,097,152 total
  int e8 = gid & 31;
  int row = gid >> 5;         // row = t*128 + b
  int b = row & 127;
  int t = row >> 7;
  int word = sent[b * T_ + t];
  const float* src = emb + (size_t)word * E_ + e8 * 8;
  float4 v0 = *(const float4*)(src);
  float4 v1 = *(const float4*)(src + 4);
  _Float16 o[8] = {(_Float16)v0.x, (_Float16)v0.y, (_Float16)v0.z, (_Float16)v0.w,
                   (_Float16)v1.x, (_Float16)v1.y, (_Float16)v1.z, (_Float16)v1.w};
  _Float16* dst = X + (size_t)row * E_ + e8 * 8;
  *(half4*)dst = *(half4*)o;
  *(half4*)(dst + 4) = *(half4*)(o + 4);
}

__global__ __launch_bounds__(512, 1) void lstm_kernel(
    const _Float16* __restrict__ X,
    const float* __restrict__ Wx, const float* __restrict__ Wh,
    const float* __restrict__ bias,
    u32t* __restrict__ Ht, u32t* FlagA) {
  // LDS: Hs [16][HROW_] fp16 (16,512) | Rs float[4][512] (8,192) = 24,704
  // used; block padded to 96 KB to keep the proven 1-wg/CU spread.
  __shared__ __align__(16) char smem[98304];
  _Float16* Hs = (_Float16*)smem;
  float* Rs = (float*)(smem + 16512);

  const int bid = blockIdx.x;
  const int d = bid & 7;    // domain: rows d*16 .. d*16+15 (one XCD under RR)
  const int s = bid >> 3;   // unit slice: units s*32 .. s*32+31
  const int tid = threadIdx.x;
  const int lane = tid & 63;
  const int wave = tid >> 6;      // 8 waves
  const int p16 = lane & 15;
  const int quad = lane >> 4;
  const int sg = wave & 3;        // unit subgroup (8 units)
  const int kh = wave >> 2;       // K half; kh0 also does epilogue

  // ---- one-time: gather this wave's B-fragments into VGPRs (R10-verbatim) ----
  const int C0 = ((p16 >> 3) & 1) * 512 + s * 32 + sg * 8 + (p16 & 7);  // i/f
  const int C1 = C0 + 1024;                                             // g/o
  half4 b0r[24], b1r[24];
#pragma unroll
  for (int i = 0; i < 24; ++i) {
    int kb = (i < 8) ? (kh * 8 + i) : (16 + kh * 16 + (i - 8));
#pragma unroll
    for (int j = 0; j < 4; ++j) {
      int gk = kb * 16 + quad * 4 + j;
      float w0 = (gk < E_) ? Wx[(size_t)gk * 2048 + C0]
                           : Wh[(size_t)(gk - E_) * 2048 + C0];
      float w1 = (gk < E_) ? Wx[(size_t)gk * 2048 + C1]
                           : Wh[(size_t)(gk - E_) * 2048 + C1];
      b0r[i][j] = (_Float16)w0;
      b1r[i][j] = (_Float16)w1;
    }
  }

  const bool lo = (p16 < 8);
  const int uo = p16 & 7;
  const int gu = s * 32 + sg * 8 + uo;               // global unit id
  const float bias0 = bias[(lo ? 0 : 512) + gu];     // i or f
  const float bias1 = bias[(lo ? 1024 : 1536) + gu]; // g or o

  float cst[4] = {0.f, 0.f, 0.f, 0.f};  // c-state (kh0 waves, lo lanes)

  const int brow = d * 16 + p16;   // A-frag batch row
  const int ko = quad * 4;
  const u64t TM = 0xffff0000ffff0000ULL;

  for (int t = 0; t < T_; ++t) {
    const int pin = t & 1, pout = pin ^ 1;

    floatx4 acc0 = {0.f, 0.f, 0.f, 0.f};
    floatx4 acc1 = {0.f, 0.f, 0.f, 0.f};

    // ---- phase A: x-blocks (8/wave), no h dependency ----
    const _Float16* xr = X + ((size_t)t * B_ + brow) * E_ + ko;
#pragma unroll
    for (int i = 0; i < 8; ++i) {
      half4 a = *(const half4*)(xr + (kh * 8 + i) * 16);
      acc0 = MFMA16(a, b0r[i], acc0, 0, 0, 0);
      acc1 = MFMA16(a, b1r[i], acc1, 0, 0, 0);
    }

    if (t > 0) {
      const u32t tgt = (u32t)t;

      // ---- hint: budgeted volatile poll of 64 per-wave flags (XCD L2) ----
      {
        const volatile u32t* fa = FlagA + (size_t)(pin * 8 + d) * 64;
        int budget = 24;
        for (;;) {
          u32t v = fa[lane];
          if (__all(v == tgt) || --budget <= 0) break;
          __builtin_amdgcn_s_sleep(1);
        }
      }

      // ---- gate: parallel agent tagged masked retry (R4-proven) ----
      // chunk j: row r = wave*2 + (j>>2), seg = j&3; lane -> u64 of units
      // seg*128 + lane*2 (contiguous, 512B/instr, PARALLEL loads).
      const u32t* hq = Ht + (size_t)(pin * 8 + d) * 16 * 512;
      u64t hv[8];
      const u64t tp = ((u64t)tgt << 48) | ((u64t)tgt << 16);
      u32t done = 0;
      for (;;) {
#pragma unroll
        for (int j = 0; j < 8; ++j) {
          if (!((done >> j) & 1)) {
            const u64t* src =
                (const u64t*)(hq + (size_t)(wave * 2 + (j >> 2)) * 512 +
                              (j & 3) * 128) + lane;
            hv[j] = __hip_atomic_load(src, __ATOMIC_RELAXED,
                                      __HIP_MEMORY_SCOPE_AGENT);
          }
        }
        u32t nd = done;
#pragma unroll
        for (int j = 0; j < 8; ++j) {
          if (!((nd >> j) & 1)) {
            if (((hv[j] ^ tp) & TM) == 0) nd |= (1u << j);
          }
        }
        done = nd;
        if (__all(done == 0xffu)) break;
        __builtin_amdgcn_s_sleep(1);
      }
      // strip tags -> fp16 slab
#pragma unroll
      for (int j = 0; j < 8; ++j) {
        int r = wave * 2 + (j >> 2), seg = j & 3;
        u32t packed = ((u32t)hv[j] & 0xffffu) |
                      ((u32t)(hv[j] >> 16) & 0xffff0000u);
        *(u32t*)(Hs + r * HROW_ + seg * 128 + lane * 2) = packed;
      }
    }
    __syncthreads();  // B2: slab ready (uniform: all waves, every t)

    if (t > 0) {
      // ---- phase C: h-blocks (16/wave) from slab ----
#pragma unroll
      for (int i = 0; i < 16; ++i) {
        half4 a = *(const half4*)(Hs + p16 * HROW_ + (kh * 16 + i) * 16 + ko);
        acc0 = MFMA16(a, b0r[8 + i], acc0, 0, 0, 0);
        acc1 = MFMA16(a, b1r[8 + i], acc1, 0, 0, 0);
      }
    }

    // ---- kh1 partials -> Rs ----
    if (kh == 1) {
      float* wb = Rs + sg * 512;
      *(floatx4*)(wb + lane * 4) = acc0;
      *(floatx4*)(wb + 256 + lane * 4) = acc1;
    }
    __syncthreads();  // B3: partials ready

    // ---- epilogue (kh0): reduce, gates, tagged publish + wave flag ----
    if (kh == 0) {
      const float* rb = Rs + sg * 512;
      floatx4 z0v = acc0 + *(const floatx4*)(rb + lane * 4);
      floatx4 z1v = acc1 + *(const floatx4*)(rb + 256 + lane * 4);
#pragma unroll
      for (int r = 0; r < 4; ++r) {
        float z0 = z0v[r] + bias0;  // i (lo) / f (hi)
        float z1 = z1v[r] + bias1;  // g (lo) / o (hi)
        float s0 = sigmf(z0);
        float s1 = lo ? tanh_f(z1) : sigmf(z1);
        float prod = s0 * s1;                          // i*g on lo lanes
        float fg = __shfl_xor(lo ? prod : s0, 8, 64);  // lo receives f
        float og = __shfl_xor(s1, 8, 64);              // lo receives o
        if (lo) {
          float cn = fg * cst[r] + prod;
          cst[r] = cn;
          float h = og * tanh_f(cn);
          int rowl = quad * 4 + r;                     // local row in domain
          _Float16 hf16 = (_Float16)h;
          u32t hb = ((u32t)(t + 1) << 16) |
                    (u32t)__builtin_bit_cast(unsigned short, hf16);
          __hip_atomic_store(
              &Ht[((size_t)(pout * 8 + d) * 16 + rowl) * 512 + gu], hb,
              __ATOMIC_RELAXED, __HIP_MEMORY_SCOPE_AGENT);
        }
      }
      // per-wave hint flag (no drain, no barrier; tags gate correctness)
      if (lane == 0)
        *(volatile u32t*)(FlagA + (size_t)(pout * 8 + d) * 64 + s * 4 + sg) =
            (u32t)(t + 1);
    }
    // no end barrier.
  }
}

// MLP head: one block per batch row. h(512)->relu 128->relu 64->sigmoid 1.
// T=512 even -> final h in Ht parity 0 (tag 512). Kernel boundary orders it.
__global__ void head_kernel(const u32t* __restrict__ Ht,
                            const float* __restrict__ W1, const float* __restrict__ b1,
                            const float* __restrict__ W2, const float* __restrict__ b2,
                            const float* __restrict__ W3, const float* __restrict__ b3,
                            float* __restrict__ out) {
  __shared__ float hs[512];
  __shared__ float h1[128];
  __shared__ float h2[64];
  int row = blockIdx.x;
  int tid = threadIdx.x;  // 128 threads
  int dd = row >> 4, rr = row & 15;
  const u32t* hrow = Ht + ((size_t)dd * 16 + rr) * 512;
  for (int k = tid; k < 512; k += 128) {
    unsigned short hb = (unsigned short)(hrow[k] & 0xffffu);
    hs[k] = (float)__builtin_bit_cast(_Float16, hb);
  }
  __syncthreads();
  float a = b1[tid];
  for (int k = 0; k < 512; ++k) a += hs[k] * W1[k * 128 + tid];
  h1[tid] = fmaxf(a, 0.0f);
  __syncthreads();
  if (tid < 64) {
    float a2 = b2[tid];
    for (int k = 0; k < 128; ++k) a2 += h1[k] * W2[k * 64 + tid];
    h2[tid] = fmaxf(a2, 0.0f);
  }
  __syncthreads();
  if (tid == 0) {
    float a3 = b3[0];
    for (int k = 0; k < 64; ++k) a3 += h2[k] * W3[k];
    out[row] = 1.0f / (1.0f + __expf(-a3));
  }
}

extern "C" void kernel_launch(void* const* d_in, const int* in_sizes, int n_in,
                              void* d_out, int out_size, void* d_ws, size_t ws_size,
                              hipStream_t stream) {
  const int* sent = (const int*)d_in[0];
  const float* emb = (const float*)d_in[1];
  const float* Wx = (const float*)d_in[2];
  const float* Wh = (const float*)d_in[3];
  const float* b = (const float*)d_in[4];
  const float* W1 = (const float*)d_in[5];
  const float* b1 = (const float*)d_in[6];
  const float* W2 = (const float*)d_in[7];
  const float* b2 = (const float*)d_in[8];
  const float* W3 = (const float*)d_in[9];
  const float* b3 = (const float*)d_in[10];
  float* out = (float*)d_out;

  char* ws = (char*)d_ws;
  _Float16* X = (_Float16*)(ws);
  u32t* Ht = (u32t*)(ws + (size_t)33554432);
  u32t* FlagA = (u32t*)(ws + (size_t)33554432 + 524288);

  prep_x_kernel<<<8192, 256, 0, stream>>>(sent, emb, X);
  lstm_kernel<<<NWG_, 512, 0, stream>>>(X, Wx, Wh, b, Ht, FlagA);
  head_kernel<<<128, 128, 0, stream>>>(Ht, W1, b1, W2, b2, W3, b3, out);
}

// Round 14
// 2345.171 us; speedup vs baseline: 1.7952x; 1.7952x over previous
//
#include <hip/hip_runtime.h>
#include <hip/hip_bf16.h>
#include <hip/hip_fp16.h>

// LSTM_RNN: B=128, T=512, E=256, U=512. R14 = R11 + producer/consumer WAVE
// SPECIALIZATION: exchange waves overlap the x-GEMM waves (m114 co-schedule).
//   - Layout (R10/R11-proven): 128 wgs = 8 domains (d = bid&7, 16 rows,
//     XCD-local under round-robin) x 16 slices (32 units / 128 gate cols).
//     Weights in VGPRs; LDS padded to 96 KB -> 1 wg/CU.
//   - NEW split: kh1 waves (4..7) run the ENTIRE x-GEMM (16 K16-blocks each,
//     + h cols [256,512) after B2). kh0 waves (0..3) run NO x: they poll the
//     domain flags and bulk-load + stage the whole 16-row slab (8 chunks of
//     512B each) while kh1 computes x -> per-step cost = max(exchange,
//     x-GEMM) instead of sum (R11 paid the bulk LLC RT serially after x).
//     kh0 then does h cols [0,256) + epilogue. Separate instruction streams
//     -> no vmcnt in-order hazard (R12's failure mode).
//   - Handshake R11-verbatim: agent fp16 h stores -> B4 vmcnt drain -> dual
//     flag (volatile XCD-L2 + agent LLC); consumer budget-20 volatile poll
//     then agent fallback; dep-offset pins bulk after poll. 3 barriers/step.
//   - No init kernels: t=0 skips detect (h0=0); 0xAA flag poison never
//     matches t in [1,512]. WAR: parity + B4/B2 induction (R11-proven).
// ws layout (~33.8 MiB):
//   X     fp16 [T][B][E]        @ 0          (33,554,432 B)
//   Hq    fp16 [2][8][16][512]  @ 33,554,432 (262,144 B)
//   FlagA u32  [2][8][16]       @ 33,816,576 (1,024 B)  volatile/L2 copy
//   FlagB u32  [2][8][16]       @ 33,817,600 (1,024 B)  agent/LLC copy

#define B_ 128
#define T_ 512
#define E_ 256
#define U_ 512
#define NWG_ 128
#define HROW_ 516   // Hs row stride (halves)

typedef __attribute__((ext_vector_type(4))) _Float16 half4;
typedef __attribute__((ext_vector_type(4))) float floatx4;
typedef unsigned long long u64t;
typedef unsigned int u32t;

#define MFMA16 __builtin_amdgcn_mfma_f32_16x16x16f16

__device__ __forceinline__ float sigmf(float x) { return 1.0f / (1.0f + __expf(-x)); }
__device__ __forceinline__ float tanh_f(float x) { return 2.0f / (1.0f + __expf(-2.0f * x)) - 1.0f; }

// X[t][b][e] = (fp16) emb[sentence[b][t]][e]; one thread = 8 elements.
__global__ void prep_x_kernel(const int* __restrict__ sent,
                              const float* __restrict__ emb,
                              _Float16* __restrict__ X) {
  int gid = blockIdx.x * blockDim.x + threadIdx.x;  // 2,097,152 total
  int e8 = gid & 31;
  int row = gid >> 5;         // row = t*128 + b
  int b = row & 127;
  int t = row >> 7;
  int word = sent[b * T_ + t];
  const float* src = emb + (size_t)word * E_ + e8 * 8;
  float4 v0 = *(const float4*)(src);
  float4 v1 = *(const float4*)(src + 4);
  _Float16 o[8] = {(_Float16)v0.x, (_Float16)v0.y, (_Float16)v0.z, (_Float16)v0.w,
                   (_Float16)v1.x, (_Float16)v1.y, (_Float16)v1.z, (_Float16)v1.w};
  _Float16* dst = X + (size_t)row * E_ + e8 * 8;
  *(half4*)dst = *(half4*)o;
  *(half4*)(dst + 4) = *(half4*)(o + 4);
}

__global__ __launch_bounds__(512, 1) void lstm_kernel(
    const _Float16* __restrict__ X,
    const float* __restrict__ Wx, const float* __restrict__ Wh,
    const float* __restrict__ bias,
    _Float16* __restrict__ Hq, u32t* FlagA, u32t* FlagB) {
  // LDS: Hs [16][HROW_] fp16 (16,512) | Rs float[4][512] (8,192) = 24,704
  // used; block padded to 96 KB to keep the proven 1-wg/CU spread.
  __shared__ __align__(16) char smem[98304];
  _Float16* Hs = (_Float16*)smem;
  float* Rs = (float*)(smem + 16512);

  const int bid = blockIdx.x;
  const int d = bid & 7;    // domain: rows d*16 .. d*16+15 (one XCD under RR)
  const int s = bid >> 3;   // unit slice: units s*32 .. s*32+31
  const int tid = threadIdx.x;
  const int lane = tid & 63;
  const int wave = tid >> 6;      // 8 waves
  const int p16 = lane & 15;
  const int quad = lane >> 4;
  const int sg = wave & 3;        // unit subgroup (8 units)
  const int kh = wave >> 2;       // 0: exchange + h[0,256) + epilogue
                                  // 1: x-GEMM + h[256,512)

  // ---- one-time: gather this wave's B-fragments into VGPRs ----
  // kh0: 16 h-blocks (cols 0..255)   -> b0r[i], kb = 16+i,  i in [0,16)
  // kh1: 16 x-blocks + 16 h-blocks (cols 256..511)
  //      -> b0r[i]: i<16: kb = i (x); i>=16: kb = 16+i (h hi), i in [0,32)
  const int C0 = ((p16 >> 3) & 1) * 512 + s * 32 + sg * 8 + (p16 & 7);  // i/f
  const int C1 = C0 + 1024;                                             // g/o
  half4 b0r[32], b1r[32];
  if (kh == 0) {
#pragma unroll
    for (int i = 0; i < 16; ++i) {
      int kb = 16 + i;
#pragma unroll
      for (int j = 0; j < 4; ++j) {
        int gk = kb * 16 + quad * 4 + j;
        b0r[i][j] = (_Float16)Wh[(size_t)(gk - E_) * 2048 + C0];
        b1r[i][j] = (_Float16)Wh[(size_t)(gk - E_) * 2048 + C1];
      }
    }
  } else {
#pragma unroll
    for (int i = 0; i < 32; ++i) {
      int kb = (i < 16) ? i : (16 + i);
#pragma unroll
      for (int j = 0; j < 4; ++j) {
        int gk = kb * 16 + quad * 4 + j;
        float w0 = (gk < E_) ? Wx[(size_t)gk * 2048 + C0]
                             : Wh[(size_t)(gk - E_) * 2048 + C0];
        float w1 = (gk < E_) ? Wx[(size_t)gk * 2048 + C1]
                             : Wh[(size_t)(gk - E_) * 2048 + C1];
        b0r[i][j] = (_Float16)w0;
        b1r[i][j] = (_Float16)w1;
      }
    }
  }

  const bool lo = (p16 < 8);
  const int uo = p16 & 7;
  const int gu = s * 32 + sg * 8 + uo;               // global unit id
  const float bias0 = bias[(lo ? 0 : 512) + gu];     // i or f
  const float bias1 = bias[(lo ? 1024 : 1536) + gu]; // g or o

  float cst[4] = {0.f, 0.f, 0.f, 0.f};  // c-state (kh0 waves, lo lanes)

  const int brow = d * 16 + p16;   // A-frag batch row
  const int ko = quad * 4;

  for (int t = 0; t < T_; ++t) {
    const int pin = t & 1, pout = pin ^ 1;

    floatx4 acc0 = {0.f, 0.f, 0.f, 0.f};
    floatx4 acc1 = {0.f, 0.f, 0.f, 0.f};

    if (kh == 1) {
      // ---- x-GEMM (kh1 only): 16 K16-blocks ----
      const _Float16* xr = X + ((size_t)t * B_ + brow) * E_ + ko;
#pragma unroll
      for (int i = 0; i < 16; ++i) {
        half4 a = *(const half4*)(xr + i * 16);
        acc0 = MFMA16(a, b0r[i], acc0, 0, 0, 0);
        acc1 = MFMA16(a, b1r[i], acc1, 0, 0, 0);
      }
    } else if (t > 0) {
      // ---- exchange (kh0 only): poll + bulk + stage, overlaps kh1's x ----
      const volatile u32t* fa = FlagA + (size_t)(pin * 8 + d) * 16;
      const u32t* fb = FlagB + (size_t)(pin * 8 + d) * 16;
      const u32t tgt = (u32t)t;
      int budget = 20;
      u32t v;
      for (;;) {
        v = (budget > 0)
                ? fa[p16]
                : __hip_atomic_load(fb + p16, __ATOMIC_RELAXED,
                                    __HIP_MEMORY_SCOPE_AGENT);
        if (__all(v == tgt)) break;
        --budget;
        __builtin_amdgcn_s_sleep(1);
      }
      const size_t dep = (size_t)(v >> 16);  // always 0; addr dependency

      // bulk: 4 rows/wave (rows wave*4 .. wave*4+3), 8 chunks of 512B
      const _Float16* hq =
          Hq + ((size_t)(pin * 8 + d) * 16 + wave * 4) * 512 + dep;
      u64t hv[8];
#pragma unroll
      for (int j = 0; j < 8; ++j) {
        size_t idx = (size_t)(j >> 1) * 128 + (j & 1) * 64 + lane;
        hv[j] = __hip_atomic_load((const u64t*)hq + idx, __ATOMIC_RELAXED,
                                  __HIP_MEMORY_SCOPE_AGENT);
      }
#pragma unroll
      for (int j = 0; j < 8; ++j) {
        int r = wave * 4 + (j >> 1), half = j & 1;
        *(u64t*)(Hs + r * HROW_ + half * 256 + lane * 4) = hv[j];
      }
    }
    __syncthreads();  // B2: slab ready + x partial-accs in flight

    if (t > 0) {
      // ---- h-GEMM from slab: kh0 -> cols [0,256), kh1 -> [256,512) ----
#pragma unroll
      for (int i = 0; i < 16; ++i) {
        int hk = kh * 16 + i;
        half4 a = *(const half4*)(Hs + p16 * HROW_ + hk * 16 + ko);
        const int wi = (kh == 0) ? i : (16 + i);
        acc0 = MFMA16(a, b0r[wi], acc0, 0, 0, 0);
        acc1 = MFMA16(a, b1r[wi], acc1, 0, 0, 0);
      }
    }

    // ---- kh1 partials -> Rs ----
    if (kh == 1) {
      float* wb = Rs + sg * 512;
      *(floatx4*)(wb + lane * 4) = acc0;
      *(floatx4*)(wb + 256 + lane * 4) = acc1;
    }
    __syncthreads();  // B3: partials ready

    // ---- epilogue (kh0): reduce, gates, fp16 publish ----
    if (kh == 0) {
      const float* rb = Rs + sg * 512;
      floatx4 z0v = acc0 + *(const floatx4*)(rb + lane * 4);
      floatx4 z1v = acc1 + *(const floatx4*)(rb + 256 + lane * 4);
#pragma unroll
      for (int r = 0; r < 4; ++r) {
        float z0 = z0v[r] + bias0;  // i (lo) / f (hi)
        float z1 = z1v[r] + bias1;  // g (lo) / o (hi)
        float s0 = sigmf(z0);
        float s1 = lo ? tanh_f(z1) : sigmf(z1);
        float prod = s0 * s1;                          // i*g on lo lanes
        float fg = __shfl_xor(lo ? prod : s0, 8, 64);  // lo receives f
        float og = __shfl_xor(s1, 8, 64);              // lo receives o
        if (lo) {
          float cn = fg * cst[r] + prod;
          cst[r] = cn;
          float h = og * tanh_f(cn);
          int rowl = quad * 4 + r;                     // local row in domain
          _Float16 hf16 = (_Float16)h;
          unsigned short hb = __builtin_bit_cast(unsigned short, hf16);
          __hip_atomic_store(
              (unsigned short*)(Hq +
                                ((size_t)(pout * 8 + d) * 16 + rowl) * 512 + gu),
              hb, __ATOMIC_RELAXED, __HIP_MEMORY_SCOPE_AGENT);
        }
      }
    }

    // ---- B4: drain vmcnt(0) for ALL waves (h at LLC) -> dual flag ----
    __syncthreads();
    if (tid == 0) {
      size_t fo = (size_t)(pout * 8 + d) * 16 + s;
      *(volatile u32t*)(FlagA + fo) = (u32t)(t + 1);   // XCD-L2 copy
      __hip_atomic_store(FlagB + fo, (u32t)(t + 1), __ATOMIC_RELAXED,
                         __HIP_MEMORY_SCOPE_AGENT);    // LLC copy
    }
  }
}

// MLP head: one block per batch row. h(512)->relu 128->relu 64->sigmoid 1.
// T=512 even -> final h in Hq parity 0. Kernel boundary orders prior stores.
__global__ void head_kernel(const _Float16* __restrict__ Hq,
                            const float* __restrict__ W1, const float* __restrict__ b1,
                            const float* __restrict__ W2, const float* __restrict__ b2,
                            const float* __restrict__ W3, const float* __restrict__ b3,
                            float* __restrict__ out) {
  __shared__ float hs[512];
  __shared__ float h1[128];
  __shared__ float h2[64];
  int row = blockIdx.x;
  int tid = threadIdx.x;  // 128 threads
  int dd = row >> 4, rr = row & 15;
  const _Float16* hrow = Hq + ((size_t)dd * 16 + rr) * 512;
  for (int k = tid; k < 512; k += 128) hs[k] = (float)hrow[k];
  __syncthreads();
  float a = b1[tid];
  for (int k = 0; k < 512; ++k) a += hs[k] * W1[k * 128 + tid];
  h1[tid] = fmaxf(a, 0.0f);
  __syncthreads();
  if (tid < 64) {
    float a2 = b2[tid];
    for (int k = 0; k < 128; ++k) a2 += h1[k] * W2[k * 64 + tid];
    h2[tid] = fmaxf(a2, 0.0f);
  }
  __syncthreads();
  if (tid == 0) {
    float a3 = b3[0];
    for (int k = 0; k < 64; ++k) a3 += h2[k] * W3[k];
    out[row] = 1.0f / (1.0f + __expf(-a3));
  }
}

extern "C" void kernel_launch(void* const* d_in, const int* in_sizes, int n_in,
                              void* d_out, int out_size, void* d_ws, size_t ws_size,
                              hipStream_t stream) {
  const int* sent = (const int*)d_in[0];
  const float* emb = (const float*)d_in[1];
  const float* Wx = (const float*)d_in[2];
  const float* Wh = (const float*)d_in[3];
  const float* b = (const float*)d_in[4];
  const float* W1 = (const float*)d_in[5];
  const float* b1 = (const float*)d_in[6];
  const float* W2 = (const float*)d_in[7];
  const float* b2 = (const float*)d_in[8];
  const float* W3 = (const float*)d_in[9];
  const float* b3 = (const float*)d_in[10];
  float* out = (float*)d_out;

  char* ws = (char*)d_ws;
  _Float16* X = (_Float16*)(ws);
  _Float16* Hq = (_Float16*)(ws + (size_t)33554432);
  u32t* FlagA = (u32t*)(ws + (size_t)33554432 + 262144);
  u32t* FlagB = (u32t*)(ws + (size_t)33554432 + 263168);

  prep_x_kernel<<<8192, 256, 0, stream>>>(sent, emb, X);
  lstm_kernel<<<NWG_, 512, 0, stream>>>(X, Wx, Wh, b, Hq, FlagA, FlagB);
  head_kernel<<<128, 128, 0, stream>>>(Hq, W1, b1, W2, b2, W3, b3, out);
}